// Round 9
// baseline (683.176 us; speedup 1.0000x reference)
//
#include <hip/hip_runtime.h>
#include <hip/hip_bf16.h>

// MHA fwd: B=2, S=2048, D=256, H=8, Dh=32.
// Outputs: out [2,2048,256] fp32, attn_mean [2,2048,2048] fp32 (concat in d_out).
//
// R8: 2-deep rotating register prefetch in attn_flash / attn_write.
// Evidence R2/R3/R6/R7: S^2 kernels invariant to waves, loads/output, LDS,
// exp cost -> bound by per-iteration latency exposure (loads issued and
// consumed in the same iteration; all waves stall in phase on waitcnt).
// Prefetch i+2 while computing i keeps ~2 compute-iterations of slack in
// flight per wave. Math/layouts identical to R7.

#define B_   2
#define S_   2048
#define D_   256
#define H_   8
#define DH_  32
#define NROW (B_*S_)      // 4096
#define KSPLIT 4
#define KKEYS (S_/KSPLIT) // 512

typedef __attribute__((ext_vector_type(8))) short bf16x8;  // 8 bf16 (4 VGPRs)
typedef __attribute__((ext_vector_type(4))) float f32x4;

__device__ __forceinline__ f32x4 mfma_bf16(bf16x8 a, bf16x8 b, f32x4 c) {
    return __builtin_amdgcn_mfma_f32_16x16x32_bf16(a, b, c, 0, 0, 0);
}

__device__ __forceinline__ float fast_exp2(float x) {
    return __builtin_amdgcn_exp2f(x);   // v_exp_f32
}

__device__ __forceinline__ unsigned short f2bf_bits(float v) {
    __hip_bfloat16 h = __float2bfloat16(v);
    return *reinterpret_cast<unsigned short*>(&h);
}

// fragment-linear index for a row-major [R x 256] matrix element (m, k)
__device__ __forceinline__ size_t fragidx(int m, int k) {
    return (size_t)(m >> 4) * 4096 + (k >> 5) * 512 + ((k >> 3) & 3) * 128
           + (m & 15) * 8 + (k & 7);
}

// ---------------- split fp32 -> (hi, lo) bf16, fragment-linear, one launch ----------------
__global__ void split_all(const float4* __restrict__ x,
                          const float4* __restrict__ wq, const float4* __restrict__ wk,
                          const float4* __restrict__ wv, const float4* __restrict__ wc,
                          ushort4* __restrict__ xh, ushort4* __restrict__ xl,
                          ushort4* __restrict__ wqh, ushort4* __restrict__ wql,
                          ushort4* __restrict__ wkh, ushort4* __restrict__ wkl,
                          ushort4* __restrict__ wvh, ushort4* __restrict__ wvl,
                          ushort4* __restrict__ wch, ushort4* __restrict__ wcl) {
    int i = blockIdx.x * 256 + threadIdx.x;   // total 327680 float4s
    const float4* src; ushort4 *ph, *pl; int off;
    if (i < 262144) { src = x; ph = xh; pl = xl; off = i; }
    else {
        int j = i - 262144;
        int rg = j >> 14; off = j & 16383;
        if (rg == 0)      { src = wq; ph = wqh; pl = wql; }
        else if (rg == 1) { src = wk; ph = wkh; pl = wkl; }
        else if (rg == 2) { src = wv; ph = wvh; pl = wvl; }
        else              { src = wc; ph = wch; pl = wcl; }
    }
    float4 v = src[off];
    float vv[4] = {v.x, v.y, v.z, v.w};
    ushort4 hb, lb;
    unsigned short* hp = (unsigned short*)&hb;
    unsigned short* lp = (unsigned short*)&lb;
    for (int c = 0; c < 4; c++) {
        __hip_bfloat16 h = __float2bfloat16(vv[c]);
        hp[c] = *reinterpret_cast<unsigned short*>(&h);
        lp[c] = f2bf_bits(vv[c] - __bfloat162float(h));
    }
    int m = off >> 6, k = (off & 63) * 4;
    size_t fi = fragidx(m, k);          // divisible by 4
    ph[fi >> 2] = hb;
    pl[fi >> 2] = lb;
}

// ---------------- QKV projection: y = x @ W^T + b ----------------
// grid (NROW/64=64, 4, 3), block 256 (4 waves, 2x2 wave tiles of 32x32).
__global__ __launch_bounds__(256) void qkv_gemm(
    const __hip_bfloat16* __restrict__ xh, const __hip_bfloat16* __restrict__ xl,
    const __hip_bfloat16* __restrict__ w0h, const __hip_bfloat16* __restrict__ w0l,
    const __hip_bfloat16* __restrict__ w1h, const __hip_bfloat16* __restrict__ w1l,
    const __hip_bfloat16* __restrict__ w2h, const __hip_bfloat16* __restrict__ w2l,
    const float* __restrict__ bq, const float* __restrict__ bk, const float* __restrict__ bvv,
    __hip_bfloat16* __restrict__ Qf, __hip_bfloat16* __restrict__ Kf,
    __hip_bfloat16* __restrict__ Vf)
{
    int z = blockIdx.z;
    const __hip_bfloat16* wh = (z==0) ? w0h : (z==1) ? w1h : w2h;
    const __hip_bfloat16* wl = (z==0) ? w0l : (z==1) ? w1l : w2l;
    const float* bias = (z==0) ? bq : (z==1) ? bk : bvv;
    const float sv = (z==0) ? 0.17677669529663687f * 1.4426950408889634f : 1.0f;

    int tid = threadIdx.x;
    int w = tid >> 6, lid = tid & 63, quad = lid >> 4, l15 = lid & 15;
    int row0 = blockIdx.x * 64 + (w >> 1) * 32;
    int col0 = blockIdx.y * 64 + (w & 1) * 32;

    f32x4 acc[2][2] = {};
#pragma unroll
    for (int k0 = 0; k0 < 256; k0 += 32) {
        bf16x8 ah[2], al[2], bh[2], bl[2];
        for (int mi = 0; mi < 2; mi++) {
            size_t ro = (size_t)((row0 + mi * 16) >> 4) * 4096 + (k0 >> 5) * 512 + lid * 8;
            ah[mi] = *(const bf16x8*)(xh + ro);
            al[mi] = *(const bf16x8*)(xl + ro);
        }
        for (int ni = 0; ni < 2; ni++) {
            size_t co = (size_t)((col0 + ni * 16) >> 4) * 4096 + (k0 >> 5) * 512 + lid * 8;
            bh[ni] = *(const bf16x8*)(wh + co);
            bl[ni] = *(const bf16x8*)(wl + co);
        }
        for (int mi = 0; mi < 2; mi++)
            for (int ni = 0; ni < 2; ni++) {
                acc[mi][ni] = mfma_bf16(ah[mi], bh[ni], acc[mi][ni]);
                acc[mi][ni] = mfma_bf16(ah[mi], bl[ni], acc[mi][ni]);
                acc[mi][ni] = mfma_bf16(al[mi], bh[ni], acc[mi][ni]);
            }
    }
    for (int mi = 0; mi < 2; mi++)
        for (int ni = 0; ni < 2; ni++) {
            int col = col0 + ni * 16 + l15;       // D-layout: col = lane&15
            int h = col >> 5, dh = col & 31;
            float bvl = bias[col];
            for (int r = 0; r < 4; r++) {
                int row = row0 + mi * 16 + quad * 4 + r;  // D-layout: row = quad*4+r
                int b = row >> 11, s = row & 2047;
                __hip_bfloat16 o = __float2bfloat16((acc[mi][ni][r] + bvl) * sv);
                size_t bh_base = (size_t)(b * H_ + h) * (S_ * DH_);
                if (z == 2) {
                    int oo = s & 31;
                    int slot = ((oo & 15) >> 2) * 8 + ((oo >> 4) << 2) + (oo & 3);
                    Vf[bh_base + (s >> 5) * 1024 + (dh >> 4) * 512
                       + (slot >> 3) * 128 + (dh & 15) * 8 + (slot & 7)] = o;
                } else {
                    size_t idx = bh_base + (s >> 4) * 512 + (dh >> 3) * 128
                                 + (s & 15) * 8 + (dh & 7);
                    if (z == 0) Qf[idx] = o; else Kf[idx] = o;
                }
            }
        }
}

// ---------------- flash pass: partial l and O' per (b,h,q16,ksplit) ----------------
// grid (S/64=32, H=8, B*KSPLIT=8), block 256 = 4 waves, one q16-tile per wave.
// 2-deep rotating prefetch: loads for iter i+2 issued while computing iter i.
__global__ __launch_bounds__(256) void attn_flash(
    const __hip_bfloat16* __restrict__ Qf, const __hip_bfloat16* __restrict__ Kf,
    const __hip_bfloat16* __restrict__ Vf,
    float* __restrict__ Opart, float* __restrict__ Lpart)
{
    int tid = threadIdx.x, w = tid >> 6, lid = tid & 63, quad = lid >> 4, l15 = lid & 15;
    int h = blockIdx.y;
    int b = blockIdx.z >> 2, ks = blockIdx.z & 3;
    int q0 = (blockIdx.x * 4 + w) * 16;
    size_t bh_base = (size_t)(b * H_ + h) * (S_ * DH_);
    const __hip_bfloat16* Qp = Qf + bh_base + (q0 >> 4) * 512 + lid * 8;
    const __hip_bfloat16* Kp = Kf + bh_base + lid * 8;
    const __hip_bfloat16* Vp = Vf + bh_base + lid * 8;
    bf16x8 qf = *(const bf16x8*)Qp;                 // B: n=q (lane&15), k=dh
    f32x4 zacc = {};
    f32x4 oacc[2] = {};
    float lp0 = 0.f, lp1 = 0.f;

    const int kbase = ks * KKEYS;
    const int NIT = KKEYS / 32;                     // 16
    bf16x8 KF0[2], KF1[2], VF0[2], VF1[2];
#define LOADK(s, kk) do { \
        const __hip_bfloat16* kp_ = Kp + ((kk) >> 4) * 512; \
        KF0[s] = *(const bf16x8*)kp_; \
        KF1[s] = *(const bf16x8*)(kp_ + 512); \
        const __hip_bfloat16* vp_ = Vp + ((kk) >> 5) * 1024; \
        VF0[s] = *(const bf16x8*)vp_; \
        VF1[s] = *(const bf16x8*)(vp_ + 512); \
    } while (0)

    LOADK(0, kbase);
    LOADK(1, kbase + 32);
    for (int i = 0; i < NIT; i++) {
        int s = i & 1;
        bf16x8 kf0 = KF0[s], kf1 = KF1[s], vf0 = VF0[s], vf1 = VF1[s];
        if (i + 2 < NIT) LOADK(s, kbase + 32 * (i + 2));  // in flight ~2 iters
        f32x4 c0 = mfma_bf16(kf0, qf, zacc);   // keys +quad*4+r, q=l15
        f32x4 c1 = mfma_bf16(kf1, qf, zacc);
        float e0[4], e1[4];
        for (int r = 0; r < 4; r++) {
            e0[r] = fast_exp2(c0[r]);
            e1[r] = fast_exp2(c1[r]);
        }
        lp0 += e0[0] + e0[1] + e0[2] + e0[3];
        lp1 += e1[0] + e1[1] + e1[2] + e1[3];
        union { bf16x8 v; __hip_bfloat162 h2[4]; } pu;
        pu.h2[0] = __float22bfloat162_rn(make_float2(e0[0], e0[1]));
        pu.h2[1] = __float22bfloat162_rn(make_float2(e0[2], e0[3]));
        pu.h2[2] = __float22bfloat162_rn(make_float2(e1[0], e1[1]));
        pu.h2[3] = __float22bfloat162_rn(make_float2(e1[2], e1[3]));
        oacc[0] = mfma_bf16(vf0, pu.v, oacc[0]);   // d 0..15
        oacc[1] = mfma_bf16(vf1, pu.v, oacc[1]);   // d 16..31
    }
#undef LOADK
    float lp = lp0 + lp1;
    lp += __shfl_xor(lp, 16);
    lp += __shfl_xor(lp, 32);

    size_t base = (size_t)((b * H_ + h) * KSPLIT + ks) * S_;
    if (lid < 16) Lpart[base + q0 + lid] = lp;
    f32x4* op = (f32x4*)(Opart + (base + q0 + l15) * DH_);
    op[quad] = oacc[0];
    op[quad + 4] = oacc[1];
}

// ---------------- combine: ctx = sum(O')/sum(l) -> fragment-linear hi/lo, invL ----------------
__global__ __launch_bounds__(256) void attn_combine(
    const float* __restrict__ Opart, const float* __restrict__ Lpart,
    __hip_bfloat16* __restrict__ cth, __hip_bfloat16* __restrict__ ctl,
    float* __restrict__ invL)
{
    int i = blockIdx.x * 256 + threadIdx.x;   // B*H*S*DH = 1,048,576
    int dh = i & 31;
    int s = (i >> 5) & (S_ - 1);
    int hb = i >> 16;                          // b*H+h in [0,16)
    float l = 0.f, o = 0.f;
#pragma unroll
    for (int ks = 0; ks < KSPLIT; ks++) {
        size_t base = (size_t)(hb * KSPLIT + ks) * S_ + s;
        l += Lpart[base];
        o += Opart[base * DH_ + dh];
    }
    float inv = 1.0f / l;
    float val = o * inv;
    int b = hb >> 3, h = hb & 7;
    size_t fi = fragidx(b * S_ + s, h * DH_ + dh);
    __hip_bfloat16 hv = __float2bfloat16(val);
    cth[fi] = hv;
    ctl[fi] = __float2bfloat16(val - __bfloat162float(hv));
    if (dh == 0) invL[hb * S_ + s] = inv;
}

// ---------------- attn write: head-mean probs, 16q x 256k per block ----------------
// grid (S/256=8, S/16=128, B=2) = 2048 blocks; wave w owns cols k0+w*64..+64.
// 2-deep rotating prefetch across the head loop.
__global__ __launch_bounds__(256) void attn_write(
    const __hip_bfloat16* __restrict__ Qf, const __hip_bfloat16* __restrict__ Kf,
    const float* __restrict__ invL, float* __restrict__ attn)
{
    __shared__ float invbuf[H_ * 16];
    int tid = threadIdx.x, w = tid >> 6, lid = tid & 63, quad = lid >> 4, l15 = lid & 15;
    int b = blockIdx.z;
    int q0 = blockIdx.y * 16;
    int k0 = blockIdx.x * 256 + w * 64;
    if (tid < 128) {
        int h = tid >> 4, r = tid & 15;
        invbuf[tid] = invL[(b * H_ + h) * S_ + q0 + r] * 0.125f;  // fold 1/H
    }
    __syncthreads();
    f32x4 zacc = {};
    float psum[4][4] = {};

    bf16x8 QF[2], KFr[2][4];
#define LOADH(s, hh) do { \
        size_t bb_ = (size_t)(b * H_ + (hh)) * (S_ * DH_); \
        QF[s] = *(const bf16x8*)(Qf + bb_ + (q0 >> 4) * 512 + lid * 8); \
        const __hip_bfloat16* kp_ = Kf + bb_ + (k0 >> 4) * 512 + lid * 8; \
        KFr[s][0] = *(const bf16x8*)kp_; \
        KFr[s][1] = *(const bf16x8*)(kp_ + 512); \
        KFr[s][2] = *(const bf16x8*)(kp_ + 1024); \
        KFr[s][3] = *(const bf16x8*)(kp_ + 1536); \
    } while (0)

    LOADH(0, 0);
    LOADH(1, 1);
    for (int h = 0; h < H_; h++) {
        int s = h & 1;
        bf16x8 qf = QF[s];
        bf16x8 kf0 = KFr[s][0], kf1 = KFr[s][1], kf2 = KFr[s][2], kf3 = KFr[s][3];
        if (h + 2 < H_) LOADH(s, h + 2);
        float il[4];
        for (int r = 0; r < 4; r++) il[r] = invbuf[h * 16 + quad * 4 + r];
        f32x4 c0 = mfma_bf16(qf, kf0, zacc);  // C: row=q (quad*4+r), col=key (l15)
        f32x4 c1 = mfma_bf16(qf, kf1, zacc);
        f32x4 c2 = mfma_bf16(qf, kf2, zacc);
        f32x4 c3 = mfma_bf16(qf, kf3, zacc);
        for (int r = 0; r < 4; r++) {
            psum[0][r] += fast_exp2(c0[r]) * il[r];
            psum[1][r] += fast_exp2(c1[r]) * il[r];
            psum[2][r] += fast_exp2(c2[r]) * il[r];
            psum[3][r] += fast_exp2(c3[r]) * il[r];
        }
    }
#undef LOADH
    for (int nt = 0; nt < 4; nt++)
        for (int r = 0; r < 4; r++)
            attn[(size_t)(b * S_ + q0 + quad * 4 + r) * S_ + k0 + nt * 16 + l15] =
                psum[nt][r];
}

// ---------------- output projection: out = ctx @ wc^T + bc (fp32 out) ----------------
// grid (NROW/64=64, 4), block 256 (4 waves, 2x2 wave tiles of 32x32).
__global__ __launch_bounds__(256) void out_gemm(
    const __hip_bfloat16* __restrict__ ch, const __hip_bfloat16* __restrict__ cl,
    const __hip_bfloat16* __restrict__ wh, const __hip_bfloat16* __restrict__ wl,
    const float* __restrict__ bias, float* __restrict__ out)
{
    int tid = threadIdx.x;
    int w = tid >> 6, lid = tid & 63, quad = lid >> 4, l15 = lid & 15;
    int row0 = blockIdx.x * 64 + (w >> 1) * 32;
    int col0 = blockIdx.y * 64 + (w & 1) * 32;

    f32x4 acc[2][2] = {};
#pragma unroll
    for (int k0 = 0; k0 < 256; k0 += 32) {
        bf16x8 ah[2], al[2], bh[2], bl[2];
        for (int mi = 0; mi < 2; mi++) {
            size_t ro = (size_t)((row0 + mi * 16) >> 4) * 4096 + (k0 >> 5) * 512 + lid * 8;
            ah[mi] = *(const bf16x8*)(ch + ro);
            al[mi] = *(const bf16x8*)(cl + ro);
        }
        for (int ni = 0; ni < 2; ni++) {
            size_t co = (size_t)((col0 + ni * 16) >> 4) * 4096 + (k0 >> 5) * 512 + lid * 8;
            bh[ni] = *(const bf16x8*)(wh + co);
            bl[ni] = *(const bf16x8*)(wl + co);
        }
        for (int mi = 0; mi < 2; mi++)
            for (int ni = 0; ni < 2; ni++) {
                acc[mi][ni] = mfma_bf16(ah[mi], bh[ni], acc[mi][ni]);
                acc[mi][ni] = mfma_bf16(ah[mi], bl[ni], acc[mi][ni]);
                acc[mi][ni] = mfma_bf16(al[mi], bh[ni], acc[mi][ni]);
            }
    }
    for (int mi = 0; mi < 2; mi++)
        for (int ni = 0; ni < 2; ni++) {
            int col = col0 + ni * 16 + l15;
            float bvl = bias[col];
            for (int r = 0; r < 4; r++) {
                int row = row0 + mi * 16 + quad * 4 + r;
                out[(size_t)row * 256 + col] = acc[mi][ni][r] + bvl;
            }
        }
}

extern "C" void kernel_launch(void* const* d_in, const int* in_sizes, int n_in,
                              void* d_out, int out_size, void* d_ws, size_t ws_size,
                              hipStream_t stream) {
    const float* x  = (const float*)d_in[0];
    const float* wq = (const float*)d_in[1];
    const float* bq = (const float*)d_in[2];
    const float* wk = (const float*)d_in[3];
    const float* bk = (const float*)d_in[4];
    const float* wv = (const float*)d_in[5];
    const float* bv = (const float*)d_in[6];
    const float* wc = (const float*)d_in[7];
    const float* bc = (const float*)d_in[8];

    char* ws = (char*)d_ws;
    const size_t MB = 1u << 20;
    const size_t KB128 = 128u * 1024u;
    __hip_bfloat16* xh  = (__hip_bfloat16*)(ws + 0 * MB);
    __hip_bfloat16* xl  = (__hip_bfloat16*)(ws + 2 * MB);
    __hip_bfloat16* wqh = (__hip_bfloat16*)(ws + 4 * MB + 0 * KB128);
    __hip_bfloat16* wql = (__hip_bfloat16*)(ws + 4 * MB + 1 * KB128);
    __hip_bfloat16* wkh = (__hip_bfloat16*)(ws + 4 * MB + 2 * KB128);
    __hip_bfloat16* wkl = (__hip_bfloat16*)(ws + 4 * MB + 3 * KB128);
    __hip_bfloat16* wvh = (__hip_bfloat16*)(ws + 4 * MB + 4 * KB128);
    __hip_bfloat16* wvl = (__hip_bfloat16*)(ws + 4 * MB + 5 * KB128);
    __hip_bfloat16* wch = (__hip_bfloat16*)(ws + 4 * MB + 6 * KB128);
    __hip_bfloat16* wcl = (__hip_bfloat16*)(ws + 4 * MB + 7 * KB128);
    __hip_bfloat16* Qfb = (__hip_bfloat16*)(ws + 5 * MB);
    __hip_bfloat16* Kfb = (__hip_bfloat16*)(ws + 7 * MB);
    __hip_bfloat16* Vfb = (__hip_bfloat16*)(ws + 9 * MB);
    __hip_bfloat16* cth = (__hip_bfloat16*)(ws + 11 * MB);
    __hip_bfloat16* ctl = (__hip_bfloat16*)(ws + 13 * MB);
    float* Opart = (float*)(ws + 15 * MB);                    // 16 MB (KSPLIT=4)
    float* Lpart = (float*)(ws + 31 * MB);                    // 512 KB
    float* invL  = (float*)(ws + 31 * MB + 512 * 1024);       // 128 KB

    float* outp  = (float*)d_out;
    float* attnp = outp + (size_t)NROW * D_;  // outputs concatenated: out, attention

    hipLaunchKernelGGL(split_all, dim3(1280), dim3(256), 0, stream,
                       (const float4*)x, (const float4*)wq, (const float4*)wk,
                       (const float4*)wv, (const float4*)wc,
                       (ushort4*)xh, (ushort4*)xl,
                       (ushort4*)wqh, (ushort4*)wql, (ushort4*)wkh, (ushort4*)wkl,
                       (ushort4*)wvh, (ushort4*)wvl, (ushort4*)wch, (ushort4*)wcl);

    hipLaunchKernelGGL(qkv_gemm, dim3(NROW / 64, 4, 3), dim3(256), 0, stream,
                       xh, xl, wqh, wql, wkh, wkl, wvh, wvl, bq, bk, bv, Qfb, Kfb, Vfb);

    hipLaunchKernelGGL(attn_flash, dim3(S_ / 64, H_, B_ * KSPLIT), dim3(256), 0, stream,
                       Qfb, Kfb, Vfb, Opart, Lpart);

    hipLaunchKernelGGL(attn_combine, dim3(4096), dim3(256), 0, stream,
                       Opart, Lpart, cth, ctl, invL);

    hipLaunchKernelGGL(attn_write, dim3(S_ / 256, S_ / 16, B_), dim3(256), 0, stream,
                       Qfb, Kfb, invL, attnp);

    hipLaunchKernelGGL(out_gemm, dim3(NROW / 64, 4), dim3(256), 0, stream,
                       cth, ctl, wch, wcl, bc, outp);
}

// Round 10
// 143.250 us; speedup vs baseline: 4.7691x; 4.7691x over previous
//
#include <hip/hip_runtime.h>
#include <hip/hip_bf16.h>

// MHA fwd: B=2, S=2048, D=256, H=8, Dh=32.
// Outputs: out [2,2048,256] fp32, attn_mean [2,2048,2048] fp32 (concat in d_out).
//
// R9: R8's prefetch idea, implemented correctly. R8's rotating arrays with a
// runtime index (s=i&1) forced the compiler into select/scratch emulation
// (592us, VALUBusy 91%). Here: manual unroll-by-2 with two NAMED register
// buffer sets -- compile-time structure only. Math identical to R7.

#define B_   2
#define S_   2048
#define D_   256
#define H_   8
#define DH_  32
#define NROW (B_*S_)      // 4096
#define KSPLIT 4
#define KKEYS (S_/KSPLIT) // 512

typedef __attribute__((ext_vector_type(8))) short bf16x8;  // 8 bf16 (4 VGPRs)
typedef __attribute__((ext_vector_type(4))) float f32x4;

__device__ __forceinline__ f32x4 mfma_bf16(bf16x8 a, bf16x8 b, f32x4 c) {
    return __builtin_amdgcn_mfma_f32_16x16x32_bf16(a, b, c, 0, 0, 0);
}

__device__ __forceinline__ float fast_exp2(float x) {
    return __builtin_amdgcn_exp2f(x);   // v_exp_f32
}

__device__ __forceinline__ unsigned short f2bf_bits(float v) {
    __hip_bfloat16 h = __float2bfloat16(v);
    return *reinterpret_cast<unsigned short*>(&h);
}

// fragment-linear index for a row-major [R x 256] matrix element (m, k)
__device__ __forceinline__ size_t fragidx(int m, int k) {
    return (size_t)(m >> 4) * 4096 + (k >> 5) * 512 + ((k >> 3) & 3) * 128
           + (m & 15) * 8 + (k & 7);
}

// ---------------- split fp32 -> (hi, lo) bf16, fragment-linear, one launch ----------------
__global__ void split_all(const float4* __restrict__ x,
                          const float4* __restrict__ wq, const float4* __restrict__ wk,
                          const float4* __restrict__ wv, const float4* __restrict__ wc,
                          ushort4* __restrict__ xh, ushort4* __restrict__ xl,
                          ushort4* __restrict__ wqh, ushort4* __restrict__ wql,
                          ushort4* __restrict__ wkh, ushort4* __restrict__ wkl,
                          ushort4* __restrict__ wvh, ushort4* __restrict__ wvl,
                          ushort4* __restrict__ wch, ushort4* __restrict__ wcl) {
    int i = blockIdx.x * 256 + threadIdx.x;   // total 327680 float4s
    const float4* src; ushort4 *ph, *pl; int off;
    if (i < 262144) { src = x; ph = xh; pl = xl; off = i; }
    else {
        int j = i - 262144;
        int rg = j >> 14; off = j & 16383;
        if (rg == 0)      { src = wq; ph = wqh; pl = wql; }
        else if (rg == 1) { src = wk; ph = wkh; pl = wkl; }
        else if (rg == 2) { src = wv; ph = wvh; pl = wvl; }
        else              { src = wc; ph = wch; pl = wcl; }
    }
    float4 v = src[off];
    float vv[4] = {v.x, v.y, v.z, v.w};
    ushort4 hb, lb;
    unsigned short* hp = (unsigned short*)&hb;
    unsigned short* lp = (unsigned short*)&lb;
    for (int c = 0; c < 4; c++) {
        __hip_bfloat16 h = __float2bfloat16(vv[c]);
        hp[c] = *reinterpret_cast<unsigned short*>(&h);
        lp[c] = f2bf_bits(vv[c] - __bfloat162float(h));
    }
    int m = off >> 6, k = (off & 63) * 4;
    size_t fi = fragidx(m, k);          // divisible by 4
    ph[fi >> 2] = hb;
    pl[fi >> 2] = lb;
}

// ---------------- QKV projection: y = x @ W^T + b ----------------
// grid (NROW/64=64, 4, 3), block 256 (4 waves, 2x2 wave tiles of 32x32).
__global__ __launch_bounds__(256) void qkv_gemm(
    const __hip_bfloat16* __restrict__ xh, const __hip_bfloat16* __restrict__ xl,
    const __hip_bfloat16* __restrict__ w0h, const __hip_bfloat16* __restrict__ w0l,
    const __hip_bfloat16* __restrict__ w1h, const __hip_bfloat16* __restrict__ w1l,
    const __hip_bfloat16* __restrict__ w2h, const __hip_bfloat16* __restrict__ w2l,
    const float* __restrict__ bq, const float* __restrict__ bk, const float* __restrict__ bvv,
    __hip_bfloat16* __restrict__ Qf, __hip_bfloat16* __restrict__ Kf,
    __hip_bfloat16* __restrict__ Vf)
{
    int z = blockIdx.z;
    const __hip_bfloat16* wh = (z==0) ? w0h : (z==1) ? w1h : w2h;
    const __hip_bfloat16* wl = (z==0) ? w0l : (z==1) ? w1l : w2l;
    const float* bias = (z==0) ? bq : (z==1) ? bk : bvv;
    const float sv = (z==0) ? 0.17677669529663687f * 1.4426950408889634f : 1.0f;

    int tid = threadIdx.x;
    int w = tid >> 6, lid = tid & 63, quad = lid >> 4, l15 = lid & 15;
    int row0 = blockIdx.x * 64 + (w >> 1) * 32;
    int col0 = blockIdx.y * 64 + (w & 1) * 32;

    f32x4 acc[2][2] = {};
#pragma unroll
    for (int k0 = 0; k0 < 256; k0 += 32) {
        bf16x8 ah[2], al[2], bh[2], bl[2];
        for (int mi = 0; mi < 2; mi++) {
            size_t ro = (size_t)((row0 + mi * 16) >> 4) * 4096 + (k0 >> 5) * 512 + lid * 8;
            ah[mi] = *(const bf16x8*)(xh + ro);
            al[mi] = *(const bf16x8*)(xl + ro);
        }
        for (int ni = 0; ni < 2; ni++) {
            size_t co = (size_t)((col0 + ni * 16) >> 4) * 4096 + (k0 >> 5) * 512 + lid * 8;
            bh[ni] = *(const bf16x8*)(wh + co);
            bl[ni] = *(const bf16x8*)(wl + co);
        }
        for (int mi = 0; mi < 2; mi++)
            for (int ni = 0; ni < 2; ni++) {
                acc[mi][ni] = mfma_bf16(ah[mi], bh[ni], acc[mi][ni]);
                acc[mi][ni] = mfma_bf16(ah[mi], bl[ni], acc[mi][ni]);
                acc[mi][ni] = mfma_bf16(al[mi], bh[ni], acc[mi][ni]);
            }
    }
    for (int mi = 0; mi < 2; mi++)
        for (int ni = 0; ni < 2; ni++) {
            int col = col0 + ni * 16 + l15;       // D-layout: col = lane&15
            int h = col >> 5, dh = col & 31;
            float bvl = bias[col];
            for (int r = 0; r < 4; r++) {
                int row = row0 + mi * 16 + quad * 4 + r;  // D-layout: row = quad*4+r
                int b = row >> 11, s = row & 2047;
                __hip_bfloat16 o = __float2bfloat16((acc[mi][ni][r] + bvl) * sv);
                size_t bh_base = (size_t)(b * H_ + h) * (S_ * DH_);
                if (z == 2) {
                    int oo = s & 31;
                    int slot = ((oo & 15) >> 2) * 8 + ((oo >> 4) << 2) + (oo & 3);
                    Vf[bh_base + (s >> 5) * 1024 + (dh >> 4) * 512
                       + (slot >> 3) * 128 + (dh & 15) * 8 + (slot & 7)] = o;
                } else {
                    size_t idx = bh_base + (s >> 4) * 512 + (dh >> 3) * 128
                                 + (s & 15) * 8 + (dh & 7);
                    if (z == 0) Qf[idx] = o; else Kf[idx] = o;
                }
            }
        }
}

// ---------------- flash pass: partial l and O' per (b,h,q16,ksplit) ----------------
// grid (S/64=32, H=8, B*KSPLIT=8), block 256 = 4 waves, one q16-tile per wave.
// Manual unroll-by-2 with named double buffers: loads for iter i+2 issued
// while computing iter i (named regs only -- no dynamic indexing).
__global__ __launch_bounds__(256) void attn_flash(
    const __hip_bfloat16* __restrict__ Qf, const __hip_bfloat16* __restrict__ Kf,
    const __hip_bfloat16* __restrict__ Vf,
    float* __restrict__ Opart, float* __restrict__ Lpart)
{
    int tid = threadIdx.x, w = tid >> 6, lid = tid & 63, quad = lid >> 4, l15 = lid & 15;
    int h = blockIdx.y;
    int b = blockIdx.z >> 2, ks = blockIdx.z & 3;
    int q0 = (blockIdx.x * 4 + w) * 16;
    size_t bh_base = (size_t)(b * H_ + h) * (S_ * DH_);
    const __hip_bfloat16* Qp = Qf + bh_base + (q0 >> 4) * 512 + lid * 8;
    // per-iteration stride is 1024 elems for both K and V fragment streams
    const __hip_bfloat16* Kp = Kf + bh_base + lid * 8 + (ks * KKEYS >> 4) * 512;
    const __hip_bfloat16* Vp = Vf + bh_base + lid * 8 + (ks * KKEYS >> 5) * 1024;
    bf16x8 qf = *(const bf16x8*)Qp;                 // B: n=q (lane&15), k=dh
    f32x4 zacc = {};
    f32x4 oacc[2] = {};
    float lp0 = 0.f, lp1 = 0.f;

    const int NIT = KKEYS / 32;                     // 16
    bf16x8 ka0, ka1, vaa, vab, kb0, kb1, vba, vbb;
    ka0 = *(const bf16x8*)(Kp);
    ka1 = *(const bf16x8*)(Kp + 512);
    vaa = *(const bf16x8*)(Vp);
    vab = *(const bf16x8*)(Vp + 512);
    kb0 = *(const bf16x8*)(Kp + 1024);
    kb1 = *(const bf16x8*)(Kp + 1536);
    vba = *(const bf16x8*)(Vp + 1024);
    vbb = *(const bf16x8*)(Vp + 1536);

#define FLASH_BODY(K0, K1, V0, V1)                                          \
    do {                                                                    \
        f32x4 c0 = mfma_bf16(K0, qf, zacc);                                 \
        f32x4 c1 = mfma_bf16(K1, qf, zacc);                                 \
        float e0[4], e1[4];                                                 \
        for (int r = 0; r < 4; r++) {                                       \
            e0[r] = fast_exp2(c0[r]);                                       \
            e1[r] = fast_exp2(c1[r]);                                       \
        }                                                                   \
        lp0 += e0[0] + e0[1] + e0[2] + e0[3];                               \
        lp1 += e1[0] + e1[1] + e1[2] + e1[3];                               \
        union { bf16x8 v; __hip_bfloat162 h2[4]; } pu;                      \
        pu.h2[0] = __float22bfloat162_rn(make_float2(e0[0], e0[1]));        \
        pu.h2[1] = __float22bfloat162_rn(make_float2(e0[2], e0[3]));        \
        pu.h2[2] = __float22bfloat162_rn(make_float2(e1[0], e1[1]));        \
        pu.h2[3] = __float22bfloat162_rn(make_float2(e1[2], e1[3]));        \
        oacc[0] = mfma_bf16(V0, pu.v, oacc[0]);                             \
        oacc[1] = mfma_bf16(V1, pu.v, oacc[1]);                             \
    } while (0)

    for (int i = 0; i < NIT; i += 2) {
        // iter i: consume buffer A, prefetch iter i+2 into A
        bf16x8 k0 = ka0, k1 = ka1, v0 = vaa, v1 = vab;
        if (i + 2 < NIT) {
            const __hip_bfloat16* kp_ = Kp + (i + 2) * 1024;
            const __hip_bfloat16* vp_ = Vp + (i + 2) * 1024;
            ka0 = *(const bf16x8*)kp_;
            ka1 = *(const bf16x8*)(kp_ + 512);
            vaa = *(const bf16x8*)vp_;
            vab = *(const bf16x8*)(vp_ + 512);
        }
        FLASH_BODY(k0, k1, v0, v1);
        // iter i+1: consume buffer B, prefetch iter i+3 into B
        k0 = kb0; k1 = kb1; v0 = vba; v1 = vbb;
        if (i + 3 < NIT) {
            const __hip_bfloat16* kp_ = Kp + (i + 3) * 1024;
            const __hip_bfloat16* vp_ = Vp + (i + 3) * 1024;
            kb0 = *(const bf16x8*)kp_;
            kb1 = *(const bf16x8*)(kp_ + 512);
            vba = *(const bf16x8*)vp_;
            vbb = *(const bf16x8*)(vp_ + 512);
        }
        FLASH_BODY(k0, k1, v0, v1);
    }
#undef FLASH_BODY

    float lp = lp0 + lp1;
    lp += __shfl_xor(lp, 16);
    lp += __shfl_xor(lp, 32);

    size_t base = (size_t)((b * H_ + h) * KSPLIT + ks) * S_;
    if (lid < 16) Lpart[base + q0 + lid] = lp;
    f32x4* op = (f32x4*)(Opart + (base + q0 + l15) * DH_);
    op[quad] = oacc[0];
    op[quad + 4] = oacc[1];
}

// ---------------- combine: ctx = sum(O')/sum(l) -> fragment-linear hi/lo, invL ----------------
__global__ __launch_bounds__(256) void attn_combine(
    const float* __restrict__ Opart, const float* __restrict__ Lpart,
    __hip_bfloat16* __restrict__ cth, __hip_bfloat16* __restrict__ ctl,
    float* __restrict__ invL)
{
    int i = blockIdx.x * 256 + threadIdx.x;   // B*H*S*DH = 1,048,576
    int dh = i & 31;
    int s = (i >> 5) & (S_ - 1);
    int hb = i >> 16;                          // b*H+h in [0,16)
    float l = 0.f, o = 0.f;
#pragma unroll
    for (int ks = 0; ks < KSPLIT; ks++) {
        size_t base = (size_t)(hb * KSPLIT + ks) * S_ + s;
        l += Lpart[base];
        o += Opart[base * DH_ + dh];
    }
    float inv = 1.0f / l;
    float val = o * inv;
    int b = hb >> 3, h = hb & 7;
    size_t fi = fragidx(b * S_ + s, h * DH_ + dh);
    __hip_bfloat16 hv = __float2bfloat16(val);
    cth[fi] = hv;
    ctl[fi] = __float2bfloat16(val - __bfloat162float(hv));
    if (dh == 0) invL[hb * S_ + s] = inv;
}

// ---------------- attn write: head-mean probs, 16q x 256k per block ----------------
// grid (S/256=8, S/16=128, B=2) = 2048 blocks; wave w owns cols k0+w*64..+64.
// Manual unroll-by-2 double buffer across the head loop (named regs).
__global__ __launch_bounds__(256) void attn_write(
    const __hip_bfloat16* __restrict__ Qf, const __hip_bfloat16* __restrict__ Kf,
    const float* __restrict__ invL, float* __restrict__ attn)
{
    __shared__ float invbuf[H_ * 16];
    int tid = threadIdx.x, w = tid >> 6, lid = tid & 63, quad = lid >> 4, l15 = lid & 15;
    int b = blockIdx.z;
    int q0 = blockIdx.y * 16;
    int k0 = blockIdx.x * 256 + w * 64;
    if (tid < 128) {
        int h = tid >> 4, r = tid & 15;
        invbuf[tid] = invL[(b * H_ + h) * S_ + q0 + r] * 0.125f;  // fold 1/H
    }
    __syncthreads();
    f32x4 zacc = {};
    float psum[4][4] = {};

    const size_t hstr = (size_t)S_ * DH_;
    const __hip_bfloat16* Qb = Qf + (size_t)(b * H_) * hstr + (q0 >> 4) * 512 + lid * 8;
    const __hip_bfloat16* Kb = Kf + (size_t)(b * H_) * hstr + (k0 >> 4) * 512 + lid * 8;

    bf16x8 qa, ka0, ka1, ka2, ka3, qb, kb0, kb1, kb2, kb3;
    qa  = *(const bf16x8*)Qb;
    ka0 = *(const bf16x8*)Kb;
    ka1 = *(const bf16x8*)(Kb + 512);
    ka2 = *(const bf16x8*)(Kb + 1024);
    ka3 = *(const bf16x8*)(Kb + 1536);
    qb  = *(const bf16x8*)(Qb + hstr);
    kb0 = *(const bf16x8*)(Kb + hstr);
    kb1 = *(const bf16x8*)(Kb + hstr + 512);
    kb2 = *(const bf16x8*)(Kb + hstr + 1024);
    kb3 = *(const bf16x8*)(Kb + hstr + 1536);

#define WRITE_BODY(Q, K0, K1, K2, K3, hh)                                   \
    do {                                                                    \
        float il[4];                                                        \
        for (int r = 0; r < 4; r++) il[r] = invbuf[(hh) * 16 + quad * 4 + r]; \
        f32x4 c0 = mfma_bf16(Q, K0, zacc);                                  \
        f32x4 c1 = mfma_bf16(Q, K1, zacc);                                  \
        f32x4 c2 = mfma_bf16(Q, K2, zacc);                                  \
        f32x4 c3 = mfma_bf16(Q, K3, zacc);                                  \
        for (int r = 0; r < 4; r++) {                                       \
            psum[0][r] += fast_exp2(c0[r]) * il[r];                         \
            psum[1][r] += fast_exp2(c1[r]) * il[r];                         \
            psum[2][r] += fast_exp2(c2[r]) * il[r];                         \
            psum[3][r] += fast_exp2(c3[r]) * il[r];                         \
        }                                                                   \
    } while (0)

    for (int h = 0; h < H_; h += 2) {
        bf16x8 q = qa, k0_ = ka0, k1_ = ka1, k2_ = ka2, k3_ = ka3;
        if (h + 2 < H_) {
            const __hip_bfloat16* qp = Qb + (h + 2) * hstr;
            const __hip_bfloat16* kp = Kb + (h + 2) * hstr;
            qa  = *(const bf16x8*)qp;
            ka0 = *(const bf16x8*)kp;
            ka1 = *(const bf16x8*)(kp + 512);
            ka2 = *(const bf16x8*)(kp + 1024);
            ka3 = *(const bf16x8*)(kp + 1536);
        }
        WRITE_BODY(q, k0_, k1_, k2_, k3_, h);
        q = qb; k0_ = kb0; k1_ = kb1; k2_ = kb2; k3_ = kb3;
        if (h + 3 < H_) {
            const __hip_bfloat16* qp = Qb + (h + 3) * hstr;
            const __hip_bfloat16* kp = Kb + (h + 3) * hstr;
            qb  = *(const bf16x8*)qp;
            kb0 = *(const bf16x8*)kp;
            kb1 = *(const bf16x8*)(kp + 512);
            kb2 = *(const bf16x8*)(kp + 1024);
            kb3 = *(const bf16x8*)(kp + 1536);
        }
        WRITE_BODY(q, k0_, k1_, k2_, k3_, h + 1);
    }
#undef WRITE_BODY

    for (int nt = 0; nt < 4; nt++)
        for (int r = 0; r < 4; r++)
            attn[(size_t)(b * S_ + q0 + quad * 4 + r) * S_ + k0 + nt * 16 + l15] =
                psum[nt][r];
}

// ---------------- output projection: out = ctx @ wc^T + bc (fp32 out) ----------------
// grid (NROW/64=64, 4), block 256 (4 waves, 2x2 wave tiles of 32x32).
__global__ __launch_bounds__(256) void out_gemm(
    const __hip_bfloat16* __restrict__ ch, const __hip_bfloat16* __restrict__ cl,
    const __hip_bfloat16* __restrict__ wh, const __hip_bfloat16* __restrict__ wl,
    const float* __restrict__ bias, float* __restrict__ out)
{
    int tid = threadIdx.x;
    int w = tid >> 6, lid = tid & 63, quad = lid >> 4, l15 = lid & 15;
    int row0 = blockIdx.x * 64 + (w >> 1) * 32;
    int col0 = blockIdx.y * 64 + (w & 1) * 32;

    f32x4 acc[2][2] = {};
#pragma unroll
    for (int k0 = 0; k0 < 256; k0 += 32) {
        bf16x8 ah[2], al[2], bh[2], bl[2];
        for (int mi = 0; mi < 2; mi++) {
            size_t ro = (size_t)((row0 + mi * 16) >> 4) * 4096 + (k0 >> 5) * 512 + lid * 8;
            ah[mi] = *(const bf16x8*)(ch + ro);
            al[mi] = *(const bf16x8*)(cl + ro);
        }
        for (int ni = 0; ni < 2; ni++) {
            size_t co = (size_t)((col0 + ni * 16) >> 4) * 4096 + (k0 >> 5) * 512 + lid * 8;
            bh[ni] = *(const bf16x8*)(wh + co);
            bl[ni] = *(const bf16x8*)(wl + co);
        }
        for (int mi = 0; mi < 2; mi++)
            for (int ni = 0; ni < 2; ni++) {
                acc[mi][ni] = mfma_bf16(ah[mi], bh[ni], acc[mi][ni]);
                acc[mi][ni] = mfma_bf16(ah[mi], bl[ni], acc[mi][ni]);
                acc[mi][ni] = mfma_bf16(al[mi], bh[ni], acc[mi][ni]);
            }
    }
    for (int mi = 0; mi < 2; mi++)
        for (int ni = 0; ni < 2; ni++) {
            int col = col0 + ni * 16 + l15;
            float bvl = bias[col];
            for (int r = 0; r < 4; r++) {
                int row = row0 + mi * 16 + quad * 4 + r;
                out[(size_t)row * 256 + col] = acc[mi][ni][r] + bvl;
            }
        }
}

extern "C" void kernel_launch(void* const* d_in, const int* in_sizes, int n_in,
                              void* d_out, int out_size, void* d_ws, size_t ws_size,
                              hipStream_t stream) {
    const float* x  = (const float*)d_in[0];
    const float* wq = (const float*)d_in[1];
    const float* bq = (const float*)d_in[2];
    const float* wk = (const float*)d_in[3];
    const float* bk = (const float*)d_in[4];
    const float* wv = (const float*)d_in[5];
    const float* bv = (const float*)d_in[6];
    const float* wc = (const float*)d_in[7];
    const float* bc = (const float*)d_in[8];

    char* ws = (char*)d_ws;
    const size_t MB = 1u << 20;
    const size_t KB128 = 128u * 1024u;
    __hip_bfloat16* xh  = (__hip_bfloat16*)(ws + 0 * MB);
    __hip_bfloat16* xl  = (__hip_bfloat16*)(ws + 2 * MB);
    __hip_bfloat16* wqh = (__hip_bfloat16*)(ws + 4 * MB + 0 * KB128);
    __hip_bfloat16* wql = (__hip_bfloat16*)(ws + 4 * MB + 1 * KB128);
    __hip_bfloat16* wkh = (__hip_bfloat16*)(ws + 4 * MB + 2 * KB128);
    __hip_bfloat16* wkl = (__hip_bfloat16*)(ws + 4 * MB + 3 * KB128);
    __hip_bfloat16* wvh = (__hip_bfloat16*)(ws + 4 * MB + 4 * KB128);
    __hip_bfloat16* wvl = (__hip_bfloat16*)(ws + 4 * MB + 5 * KB128);
    __hip_bfloat16* wch = (__hip_bfloat16*)(ws + 4 * MB + 6 * KB128);
    __hip_bfloat16* wcl = (__hip_bfloat16*)(ws + 4 * MB + 7 * KB128);
    __hip_bfloat16* Qfb = (__hip_bfloat16*)(ws + 5 * MB);
    __hip_bfloat16* Kfb = (__hip_bfloat16*)(ws + 7 * MB);
    __hip_bfloat16* Vfb = (__hip_bfloat16*)(ws + 9 * MB);
    __hip_bfloat16* cth = (__hip_bfloat16*)(ws + 11 * MB);
    __hip_bfloat16* ctl = (__hip_bfloat16*)(ws + 13 * MB);
    float* Opart = (float*)(ws + 15 * MB);                    // 16 MB (KSPLIT=4)
    float* Lpart = (float*)(ws + 31 * MB);                    // 512 KB
    float* invL  = (float*)(ws + 31 * MB + 512 * 1024);       // 128 KB

    float* outp  = (float*)d_out;
    float* attnp = outp + (size_t)NROW * D_;  // outputs concatenated: out, attention

    hipLaunchKernelGGL(split_all, dim3(1280), dim3(256), 0, stream,
                       (const float4*)x, (const float4*)wq, (const float4*)wk,
                       (const float4*)wv, (const float4*)wc,
                       (ushort4*)xh, (ushort4*)xl,
                       (ushort4*)wqh, (ushort4*)wql, (ushort4*)wkh, (ushort4*)wkl,
                       (ushort4*)wvh, (ushort4*)wvl, (ushort4*)wch, (ushort4*)wcl);

    hipLaunchKernelGGL(qkv_gemm, dim3(NROW / 64, 4, 3), dim3(256), 0, stream,
                       xh, xl, wqh, wql, wkh, wkl, wvh, wvl, bq, bk, bv, Qfb, Kfb, Vfb);

    hipLaunchKernelGGL(attn_flash, dim3(S_ / 64, H_, B_ * KSPLIT), dim3(256), 0, stream,
                       Qfb, Kfb, Vfb, Opart, Lpart);

    hipLaunchKernelGGL(attn_combine, dim3(4096), dim3(256), 0, stream,
                       Opart, Lpart, cth, ctl, invL);

    hipLaunchKernelGGL(attn_write, dim3(S_ / 256, S_ / 16, B_), dim3(256), 0, stream,
                       Qfb, Kfb, invL, attnp);

    hipLaunchKernelGGL(out_gemm, dim3(NROW / 64, 4), dim3(256), 0, stream,
                       cth, ctl, wch, wcl, bc, outp);
}